// Round 1
// baseline (1330.364 us; speedup 1.0000x reference)
//
#include <hip/hip_runtime.h>
#include <math.h>

#define Bv 4096
#define Sv 64
#define Ev 128
#define Hv 256
#define Cv 18
#define KA 384      // E + H (concat A = [emb | h])
#define AP 20       // At pitch in floats (padded, mult of 4 for b128 alignment)
#define KT 32       // W chunk size along k
#define Mrows 16    // sequences per block

// ---------------- kernel 0: transpose weights once into ws ----------------
// WT rows 0..127  = W_ih^T  (WT[k][c] = W_ih[c][k])
// WT rows 128..383 = W_hh^T
// WT rows 384..639 = W1^T
__global__ void build_wt(const float* __restrict__ W_ih,
                         const float* __restrict__ W_hh,
                         const float* __restrict__ W1,
                         float* __restrict__ WT) {
    int k = blockIdx.x;      // 0..639
    int c = threadIdx.x;     // 0..255
    float v;
    if (k < Ev)            v = W_ih[c * Ev + k];
    else if (k < Ev + Hv)  v = W_hh[c * Hv + (k - Ev)];
    else                   v = W1[c * Hv + (k - Ev - Hv)];
    WT[k * Hv + c] = v;
}

// ---------------- kernel 1: block-local recurrence ----------------
// Each block owns 16 sequences for all 64 steps. h lives in LDS (transposed
// At layout: At[k][r], k in [0,384), r in [0,16), pitch AP).
// Per step: C[16,256] = A[16,384] * WT[384,256], tanh, write-back, gather.
__global__ __launch_bounds__(256) void rnn_kernel(
    const int* __restrict__ x_in, const int* __restrict__ x_len,
    const float* __restrict__ emb, const float* __restrict__ WT,
    const float* __restrict__ b_ih, const float* __restrict__ b_hh,
    float* __restrict__ last)
{
    __shared__ float At[KA * AP];    // 30720 B, A transposed (k-major)
    __shared__ float Wt[KT * Hv];    // 32768 B, one k-chunk of WT

    const int tid = threadIdx.x;
    const int tr = tid & 3;          // row group: rows 4*tr .. 4*tr+3
    const int tc = tid >> 2;         // col group: cols 4*tc .. 4*tc+3
    const int rb = blockIdx.x * Mrows;

    float bc[4];
    int len[4];
    #pragma unroll
    for (int j = 0; j < 4; ++j) bc[j] = b_ih[4 * tc + j] + b_hh[4 * tc + j];
    #pragma unroll
    for (int i = 0; i < 4; ++i) len[i] = x_len[rb + 4 * tr + i];

    // h0 = 0: zero the h-part of At (k in [128,384))
    for (int idx = tid; idx < Hv * Mrows; idx += 256) {
        int k = idx >> 4, r = idx & 15;
        At[(Ev + k) * AP + r] = 0.f;
    }

    const int er = tid >> 4;          // 0..15: row for emb staging
    const int ek = (tid & 15) * 8;    // 0..120: k offset for emb staging

    #pragma unroll 1
    for (int t = 0; t < Sv; ++t) {
        // ---- stage embedding part of At (k in [0,128)) ----
        // Safe without a barrier here: previous step's GEMM reads finished at
        // the post-chunk-loop barrier; epilogue only wrote the h-part.
        {
            int idx = x_in[(rb + er) * Sv + t];
            const float4* src = reinterpret_cast<const float4*>(&emb[idx * Ev + ek]);
            float4 v0 = src[0], v1 = src[1];
            At[(ek + 0) * AP + er] = v0.x; At[(ek + 1) * AP + er] = v0.y;
            At[(ek + 2) * AP + er] = v0.z; At[(ek + 3) * AP + er] = v0.w;
            At[(ek + 4) * AP + er] = v1.x; At[(ek + 5) * AP + er] = v1.y;
            At[(ek + 6) * AP + er] = v1.z; At[(ek + 7) * AP + er] = v1.w;
        }

        float acc[4][4];
        #pragma unroll
        for (int i = 0; i < 4; ++i)
            #pragma unroll
            for (int j = 0; j < 4; ++j) acc[i][j] = 0.f;

        #pragma unroll 1
        for (int ch = 0; ch < KA / KT; ++ch) {
            __syncthreads();   // prev chunk's Wt reads done; At writes visible
            // flat coalesced copy of one 32x256 chunk of WT
            {
                const float4* src = reinterpret_cast<const float4*>(&WT[ch * KT * Hv]);
                float4* dst = reinterpret_cast<float4*>(Wt);
                #pragma unroll
                for (int q = 0; q < 8; ++q) dst[q * 256 + tid] = src[q * 256 + tid];
            }
            __syncthreads();   // Wt ready
            #pragma unroll 8
            for (int kk = 0; kk < KT; ++kk) {
                float4 a4 = *reinterpret_cast<const float4*>(&At[(ch * KT + kk) * AP + 4 * tr]);
                float4 w4 = *reinterpret_cast<const float4*>(&Wt[kk * Hv + 4 * tc]);
                float a[4] = {a4.x, a4.y, a4.z, a4.w};
                float w[4] = {w4.x, w4.y, w4.z, w4.w};
                #pragma unroll
                for (int i = 0; i < 4; ++i)
                    #pragma unroll
                    for (int j = 0; j < 4; ++j)
                        acc[i][j] = fmaf(a[i], w[j], acc[i][j]);
            }
        }
        __syncthreads();   // all GEMM reads of At done before h write-back

        // ---- epilogue: tanh, write h back into At, gather last ----
        float hn[4][4];
        #pragma unroll
        for (int i = 0; i < 4; ++i)
            #pragma unroll
            for (int j = 0; j < 4; ++j)
                hn[i][j] = tanhf(acc[i][j] + bc[j]);

        #pragma unroll
        for (int j = 0; j < 4; ++j) {
            float4 v = make_float4(hn[0][j], hn[1][j], hn[2][j], hn[3][j]);
            *reinterpret_cast<float4*>(&At[(Ev + 4 * tc + j) * AP + 4 * tr]) = v;
        }
        #pragma unroll
        for (int i = 0; i < 4; ++i) {
            if (t == len[i] - 1) {
                float4 v = make_float4(hn[i][0], hn[i][1], hn[i][2], hn[i][3]);
                *reinterpret_cast<float4*>(&last[(rb + 4 * tr + i) * Hv + 4 * tc]) = v;
            }
        }
    }
}

// ---------------- kernel 2: fused FC1(relu) + FC2 ----------------
__global__ __launch_bounds__(256) void fc_kernel(
    const float* __restrict__ last, const float* __restrict__ WT,
    const float* __restrict__ b1, const float* __restrict__ W2,
    const float* __restrict__ b2, float* __restrict__ out)
{
    __shared__ float At[Hv * AP];    // 20480 B: last tile, transposed
    __shared__ float Wt[KT * Hv];    // 32768 B; later reused as y row-major

    const int tid = threadIdx.x;
    const int tr = tid & 3;
    const int tc = tid >> 2;
    const int rb = blockIdx.x * Mrows;

    // stage last[rb..rb+15][0..255] transposed into At
    {
        const int er = tid >> 4;          // 0..15
        const int ek = (tid & 15) * 16;   // 0..240
        #pragma unroll
        for (int q = 0; q < 4; ++q) {
            float4 v = *reinterpret_cast<const float4*>(&last[(rb + er) * Hv + ek + 4 * q]);
            At[(ek + 4 * q + 0) * AP + er] = v.x;
            At[(ek + 4 * q + 1) * AP + er] = v.y;
            At[(ek + 4 * q + 2) * AP + er] = v.z;
            At[(ek + 4 * q + 3) * AP + er] = v.w;
        }
    }

    const float* W1T = WT + KA * Hv;  // rows 384..639 of WT

    float acc[4][4];
    #pragma unroll
    for (int i = 0; i < 4; ++i)
        #pragma unroll
        for (int j = 0; j < 4; ++j) acc[i][j] = 0.f;

    #pragma unroll 1
    for (int ch = 0; ch < Hv / KT; ++ch) {
        __syncthreads();
        {
            const float4* src = reinterpret_cast<const float4*>(&W1T[ch * KT * Hv]);
            float4* dst = reinterpret_cast<float4*>(Wt);
            #pragma unroll
            for (int q = 0; q < 8; ++q) dst[q * 256 + tid] = src[q * 256 + tid];
        }
        __syncthreads();
        #pragma unroll 8
        for (int kk = 0; kk < KT; ++kk) {
            float4 a4 = *reinterpret_cast<const float4*>(&At[(ch * KT + kk) * AP + 4 * tr]);
            float4 w4 = *reinterpret_cast<const float4*>(&Wt[kk * Hv + 4 * tc]);
            float a[4] = {a4.x, a4.y, a4.z, a4.w};
            float w[4] = {w4.x, w4.y, w4.z, w4.w};
            #pragma unroll
            for (int i = 0; i < 4; ++i)
                #pragma unroll
                for (int j = 0; j < 4; ++j)
                    acc[i][j] = fmaf(a[i], w[j], acc[i][j]);
        }
    }
    __syncthreads();   // Wt free for reuse

    // y = relu(acc + b1), store row-major into Wt (pitch 260)
    {
        float bj[4];
        #pragma unroll
        for (int j = 0; j < 4; ++j) bj[j] = b1[4 * tc + j];
        #pragma unroll
        for (int i = 0; i < 4; ++i) {
            float4 v;
            v.x = fmaxf(acc[i][0] + bj[0], 0.f);
            v.y = fmaxf(acc[i][1] + bj[1], 0.f);
            v.z = fmaxf(acc[i][2] + bj[2], 0.f);
            v.w = fmaxf(acc[i][3] + bj[3], 0.f);
            *reinterpret_cast<float4*>(&Wt[(4 * tr + i) * 260 + 4 * tc]) = v;
        }
    }
    __syncthreads();

    // FC2: 16 rows x 18 cols = 288 dot products of length 256
    for (int p = tid; p < Mrows * Cv; p += 256) {
        int r = p & 15, cc = p >> 4;
        float s = b2[cc];
        for (int k4 = 0; k4 < Hv / 4; ++k4) {
            float4 yv = *reinterpret_cast<const float4*>(&Wt[r * 260 + 4 * k4]);
            float4 wv = *reinterpret_cast<const float4*>(&W2[cc * Hv + 4 * k4]);
            s = fmaf(yv.x, wv.x, s);
            s = fmaf(yv.y, wv.y, s);
            s = fmaf(yv.z, wv.z, s);
            s = fmaf(yv.w, wv.w, s);
        }
        out[(rb + r) * Cv + cc] = s;
    }
}

extern "C" void kernel_launch(void* const* d_in, const int* in_sizes, int n_in,
                              void* d_out, int out_size, void* d_ws, size_t ws_size,
                              hipStream_t stream) {
    const int*   x_in  = (const int*)  d_in[0];
    const int*   x_len = (const int*)  d_in[1];
    const float* emb   = (const float*)d_in[2];
    const float* W_ih  = (const float*)d_in[3];
    const float* W_hh  = (const float*)d_in[4];
    const float* b_ih  = (const float*)d_in[5];
    const float* b_hh  = (const float*)d_in[6];
    const float* W1    = (const float*)d_in[7];
    const float* b1    = (const float*)d_in[8];
    const float* W2    = (const float*)d_in[9];
    const float* b2    = (const float*)d_in[10];
    float* out = (float*)d_out;

    float* last = (float*)d_ws;               // 4096*256 f32 = 4 MB
    float* WT   = last + Bv * Hv;             // 640*256 f32 = 640 KB

    build_wt<<<KA + Hv, 256, 0, stream>>>(W_ih, W_hh, W1, WT);
    rnn_kernel<<<Bv / Mrows, 256, 0, stream>>>(x_in, x_len, emb, WT, b_ih, b_hh, last);
    fc_kernel<<<Bv / Mrows, 256, 0, stream>>>(last, WT, b1, W2, b2, out);
}

// Round 2
// 314.402 us; speedup vs baseline: 4.2314x; 4.2314x over previous
//
#include <hip/hip_runtime.h>
#include <math.h>

#define Bv 4096
#define Sv 64
#define Ev 128
#define Hv 256
#define Cv 18
#define KA 384      // E + H
#define NKB 12      // KA/32
#define Pu 388      // Apk pitch in uint32 (97 per 16B-chunk, odd -> conflict-free b128)
#define Mrows 16
#define AP 20       // fc kernel At pitch
#define KT 32       // fc kernel chunk

using bfrag = __attribute__((ext_vector_type(8))) short;
using f4v   = __attribute__((ext_vector_type(4))) float;

__device__ inline void split_bf16(float v, unsigned& hb, unsigned& lb) {
    unsigned u = __float_as_uint(v);
    hb = (u + 0x7FFFu + ((u >> 16) & 1u)) >> 16;          // RNE bf16(v)
    float hf = __uint_as_float(hb << 16);
    float l = v - hf;
    unsigned ul = __float_as_uint(l);
    lb = (ul + 0x7FFFu + ((ul >> 16) & 1u)) >> 16;        // RNE bf16(v - hi)
}

__device__ inline unsigned pack_split(float v) {
    unsigned hb, lb;
    split_bf16(v, hb, lb);
    return (hb << 16) | lb;
}

__device__ inline float fast_tanh(float x) {
    float e = __expf(x + x);
    return 1.0f - 2.0f * __builtin_amdgcn_rcpf(e + 1.0f);
}

// ------- kernel A: build W_ih|W_hh as MFMA B-fragments (bf16 hi/lo) -------
// frag id f = (kb*16 + tile)*64 + lane ; layout: 8 uint32 = hi[0..7], lo[0..7]
__global__ void build_wfrag(const float* __restrict__ W_ih,
                            const float* __restrict__ W_hh,
                            unsigned* __restrict__ wf) {
    int f = blockIdx.x * 256 + threadIdx.x;   // 0..12287
    int lane = f & 63, tile = (f >> 6) & 15, kb = f >> 10;
    int q = lane >> 4, col = lane & 15;
    int n = tile * 16 + col;
    unsigned hs[8], ls[8];
    #pragma unroll
    for (int j = 0; j < 8; ++j) {
        int k = kb * 32 + q * 8 + j;
        float v = (k < Ev) ? W_ih[n * Ev + k] : W_hh[n * Hv + (k - Ev)];
        split_bf16(v, hs[j], ls[j]);
    }
    unsigned* o = wf + (size_t)f * 8;
    #pragma unroll
    for (int d = 0; d < 4; ++d) {
        o[d]     = hs[2 * d] | (hs[2 * d + 1] << 16);
        o[4 + d] = ls[2 * d] | (ls[2 * d + 1] << 16);
    }
}

// ------- kernel B: W1^T for the FC kernel -------
__global__ void build_w1t(const float* __restrict__ W1, float* __restrict__ W1T) {
    int k = blockIdx.x, c = threadIdx.x;
    W1T[k * Hv + c] = W1[c * Hv + k];
}

// ------- kernel C: block-local recurrence, W resident in registers -------
__global__ __launch_bounds__(256, 1) void rnn_kernel(
    const int* __restrict__ x_in, const int* __restrict__ x_len,
    const float* __restrict__ emb, const unsigned* __restrict__ wf,
    const float* __restrict__ b_ih, const float* __restrict__ b_hh,
    float* __restrict__ last)
{
    __shared__ unsigned Apk[Mrows * Pu];   // packed (hi|lo) A: k<128 emb, k>=128 h
    __shared__ int sidx[Mrows * Sv];       // token ids for this block

    const int tid = threadIdx.x;
    const int lane = tid & 63, w = tid >> 6;
    const int q = lane >> 4, col = lane & 15;
    const int rb = blockIdx.x * Mrows;

    // resident W fragments: tile (4w+i), kb -> hi/lo  (384 regs/lane)
    bfrag whi[4][NKB], wlo[4][NKB];
    {
        const bfrag* wfv = (const bfrag*)wf;
        #pragma unroll
        for (int i = 0; i < 4; ++i)
            #pragma unroll
            for (int kb = 0; kb < NKB; ++kb) {
                int base = ((kb * 16 + (4 * w + i)) * 64 + lane) * 2;
                whi[i][kb] = wfv[base];
                wlo[i][kb] = wfv[base + 1];
            }
    }

    float bc[4];
    #pragma unroll
    for (int i = 0; i < 4; ++i) {
        int n = (4 * w + i) * 16 + col;
        bc[i] = b_ih[n] + b_hh[n];
    }
    int len[4];
    #pragma unroll
    for (int r = 0; r < 4; ++r) len[r] = x_len[rb + 4 * q + r];

    // stage token ids
    for (int u = tid; u < Mrows * Sv; u += 256) sidx[u] = x_in[rb * Sv + u];
    // h0 = 0 (packed zero)
    for (int u = tid; u < Mrows * Hv; u += 256) {
        int m = u >> 8, k = u & 255;
        Apk[m * Pu + Ev + k] = 0u;
    }

    const int em = tid >> 4;           // row this thread stages emb for
    const int ek = (tid & 15) * 8;     // k offset (8 floats)

    // stage emb for t=0
    {
        int idx = x_in[(rb + em) * Sv + 0];
        const float4* ep = (const float4*)(emb + (size_t)idx * Ev + ek);
        float4 e0 = ep[0], e1 = ep[1];
        uint4* dst = (uint4*)&Apk[em * Pu + ek];
        dst[0] = make_uint4(pack_split(e0.x), pack_split(e0.y), pack_split(e0.z), pack_split(e0.w));
        dst[1] = make_uint4(pack_split(e1.x), pack_split(e1.y), pack_split(e1.z), pack_split(e1.w));
    }
    __syncthreads();

    #pragma unroll 1
    for (int t = 0; t < Sv; ++t) {
        // prefetch next step's embedding rows (latency hidden behind MFMA loop)
        float4 e0, e1;
        const bool pre = (t < Sv - 1);
        if (pre) {
            int idx = sidx[em * Sv + t + 1];
            const float4* ep = (const float4*)(emb + (size_t)idx * Ev + ek);
            e0 = ep[0]; e1 = ep[1];
        }

        f4v acc[4];
        #pragma unroll
        for (int i = 0; i < 4; ++i) { f4v z = {0.f, 0.f, 0.f, 0.f}; acc[i] = z; }

        #pragma unroll
        for (int kb = 0; kb < NKB; ++kb) {
            const uint4* ap = (const uint4*)&Apk[col * Pu + kb * 32 + q * 8];
            uint4 p0 = ap[0], p1 = ap[1];
            union { unsigned u[4]; bfrag f; } ah, al;
            ah.u[0] = (p0.x >> 16) | (p0.y & 0xFFFF0000u);
            al.u[0] = (p0.x & 0xFFFFu) | (p0.y << 16);
            ah.u[1] = (p0.z >> 16) | (p0.w & 0xFFFF0000u);
            al.u[1] = (p0.z & 0xFFFFu) | (p0.w << 16);
            ah.u[2] = (p1.x >> 16) | (p1.y & 0xFFFF0000u);
            al.u[2] = (p1.x & 0xFFFFu) | (p1.y << 16);
            ah.u[3] = (p1.z >> 16) | (p1.w & 0xFFFF0000u);
            al.u[3] = (p1.z & 0xFFFFu) | (p1.w << 16);
            #pragma unroll
            for (int i = 0; i < 4; ++i) {
                acc[i] = __builtin_amdgcn_mfma_f32_16x16x32_bf16(ah.f, whi[i][kb], acc[i], 0, 0, 0);
                acc[i] = __builtin_amdgcn_mfma_f32_16x16x32_bf16(al.f, whi[i][kb], acc[i], 0, 0, 0);
                acc[i] = __builtin_amdgcn_mfma_f32_16x16x32_bf16(ah.f, wlo[i][kb], acc[i], 0, 0, 0);
            }
        }
        __syncthreads();   // all Apk reads of this step done

        // epilogue: tanh -> pack h into Apk; gather `last`
        #pragma unroll
        for (int i = 0; i < 4; ++i) {
            int n = (4 * w + i) * 16 + col;
            #pragma unroll
            for (int r = 0; r < 4; ++r) {
                float hv = fast_tanh(acc[i][r] + bc[i]);
                int m = 4 * q + r;
                Apk[m * Pu + Ev + n] = pack_split(hv);
                if (t == len[r] - 1) last[(size_t)(rb + m) * Hv + n] = hv;
            }
        }
        if (pre) {
            uint4* dst = (uint4*)&Apk[em * Pu + ek];
            dst[0] = make_uint4(pack_split(e0.x), pack_split(e0.y), pack_split(e0.z), pack_split(e0.w));
            dst[1] = make_uint4(pack_split(e1.x), pack_split(e1.y), pack_split(e1.z), pack_split(e1.w));
        }
        __syncthreads();   // writes visible to next step
    }
}

// ------- kernel D: fused FC1(relu) + FC2 (unchanged structure) -------
__global__ __launch_bounds__(256) void fc_kernel(
    const float* __restrict__ last, const float* __restrict__ W1T,
    const float* __restrict__ b1, const float* __restrict__ W2,
    const float* __restrict__ b2, float* __restrict__ out)
{
    __shared__ float At[Hv * AP];
    __shared__ float Wt[KT * Hv];

    const int tid = threadIdx.x;
    const int tr = tid & 3;
    const int tc = tid >> 2;
    const int rb = blockIdx.x * Mrows;

    {
        const int er = tid >> 4;
        const int ek = (tid & 15) * 16;
        #pragma unroll
        for (int qq = 0; qq < 4; ++qq) {
            float4 v = *reinterpret_cast<const float4*>(&last[(rb + er) * Hv + ek + 4 * qq]);
            At[(ek + 4 * qq + 0) * AP + er] = v.x;
            At[(ek + 4 * qq + 1) * AP + er] = v.y;
            At[(ek + 4 * qq + 2) * AP + er] = v.z;
            At[(ek + 4 * qq + 3) * AP + er] = v.w;
        }
    }

    float acc[4][4];
    #pragma unroll
    for (int i = 0; i < 4; ++i)
        #pragma unroll
        for (int j = 0; j < 4; ++j) acc[i][j] = 0.f;

    #pragma unroll 1
    for (int ch = 0; ch < Hv / KT; ++ch) {
        __syncthreads();
        {
            const float4* src = reinterpret_cast<const float4*>(&W1T[ch * KT * Hv]);
            float4* dst = reinterpret_cast<float4*>(Wt);
            #pragma unroll
            for (int qq = 0; qq < 8; ++qq) dst[qq * 256 + tid] = src[qq * 256 + tid];
        }
        __syncthreads();
        #pragma unroll 8
        for (int kk = 0; kk < KT; ++kk) {
            float4 a4 = *reinterpret_cast<const float4*>(&At[(ch * KT + kk) * AP + 4 * tr]);
            float4 w4 = *reinterpret_cast<const float4*>(&Wt[kk * Hv + 4 * tc]);
            float a[4] = {a4.x, a4.y, a4.z, a4.w};
            float wv[4] = {w4.x, w4.y, w4.z, w4.w};
            #pragma unroll
            for (int i = 0; i < 4; ++i)
                #pragma unroll
                for (int j = 0; j < 4; ++j)
                    acc[i][j] = fmaf(a[i], wv[j], acc[i][j]);
        }
    }
    __syncthreads();

    {
        float bj[4];
        #pragma unroll
        for (int j = 0; j < 4; ++j) bj[j] = b1[4 * tc + j];
        #pragma unroll
        for (int i = 0; i < 4; ++i) {
            float4 v;
            v.x = fmaxf(acc[i][0] + bj[0], 0.f);
            v.y = fmaxf(acc[i][1] + bj[1], 0.f);
            v.z = fmaxf(acc[i][2] + bj[2], 0.f);
            v.w = fmaxf(acc[i][3] + bj[3], 0.f);
            *reinterpret_cast<float4*>(&Wt[(4 * tr + i) * 260 + 4 * tc]) = v;
        }
    }
    __syncthreads();

    for (int p = tid; p < Mrows * Cv; p += 256) {
        int r = p & 15, cc = p >> 4;
        float s = b2[cc];
        for (int k4 = 0; k4 < Hv / 4; ++k4) {
            float4 yv = *reinterpret_cast<const float4*>(&Wt[r * 260 + 4 * k4]);
            float4 wv = *reinterpret_cast<const float4*>(&W2[cc * Hv + 4 * k4]);
            s = fmaf(yv.x, wv.x, s);
            s = fmaf(yv.y, wv.y, s);
            s = fmaf(yv.z, wv.z, s);
            s = fmaf(yv.w, wv.w, s);
        }
        out[(rb + r) * Cv + cc] = s;
    }
}

extern "C" void kernel_launch(void* const* d_in, const int* in_sizes, int n_in,
                              void* d_out, int out_size, void* d_ws, size_t ws_size,
                              hipStream_t stream) {
    const int*   x_in  = (const int*)  d_in[0];
    const int*   x_len = (const int*)  d_in[1];
    const float* emb   = (const float*)d_in[2];
    const float* W_ih  = (const float*)d_in[3];
    const float* W_hh  = (const float*)d_in[4];
    const float* b_ih  = (const float*)d_in[5];
    const float* b_hh  = (const float*)d_in[6];
    const float* W1    = (const float*)d_in[7];
    const float* b1    = (const float*)d_in[8];
    const float* W2    = (const float*)d_in[9];
    const float* b2    = (const float*)d_in[10];
    float* out = (float*)d_out;

    float*    last = (float*)d_ws;                     // 4096*256 f32 = 4 MB
    float*    W1T  = last + (size_t)Bv * Hv;           // 256*256 f32 = 256 KB
    unsigned* wf   = (unsigned*)(W1T + Hv * Hv);       // 12288 frag-pairs * 32 B = 384 KB

    build_wfrag<<<48, 256, 0, stream>>>(W_ih, W_hh, wf);
    build_w1t<<<Hv, Hv, 0, stream>>>(W1, W1T);
    rnn_kernel<<<Bv / Mrows, 256, 0, stream>>>(x_in, x_len, emb, wf, b_ih, b_hh, last);
    fc_kernel<<<Bv / Mrows, 256, 0, stream>>>(last, W1T, b1, W2, b2, out);
}

// Round 3
// 246.220 us; speedup vs baseline: 5.4032x; 1.2769x over previous
//
#include <hip/hip_runtime.h>
#include <math.h>

#define Bv 4096
#define Sv 64
#define Ev 128
#define Hv 256
#define Cv 18
#define NKB 12      // 384 / 32
#define Mrows 16
#define AP 20       // fc kernel At pitch
#define KT 32       // fc kernel chunk

using bfrag = __attribute__((ext_vector_type(8))) short;
using f4v   = __attribute__((ext_vector_type(4))) float;

__device__ inline void split_bf16(float v, unsigned& hb, unsigned& lb) {
    unsigned u = __float_as_uint(v);
    hb = (u + 0x7FFFu + ((u >> 16) & 1u)) >> 16;          // RNE bf16(v)
    float hf = __uint_as_float(hb << 16);
    float l = v - hf;
    unsigned ul = __float_as_uint(l);
    lb = (ul + 0x7FFFu + ((ul >> 16) & 1u)) >> 16;        // RNE bf16(v - hi)
}

__device__ inline float fast_tanh(float x) {
    float e = __expf(x + x);
    return 1.0f - 2.0f * __builtin_amdgcn_rcpf(e + 1.0f);
}

// ------- kernel A: W_ih|W_hh as MFMA fragments (bf16 hi/lo), W[n][k] -------
// frag id f = (kb*16 + tile)*64 + lane ; 8 uint32 = hi[0..3], lo[0..3] packed pairs
__global__ void build_wfrag(const float* __restrict__ W_ih,
                            const float* __restrict__ W_hh,
                            unsigned* __restrict__ wf) {
    int f = blockIdx.x * 256 + threadIdx.x;   // 0..12287
    int lane = f & 63, tile = (f >> 6) & 15, kb = f >> 10;
    int q = lane >> 4, col = lane & 15;
    int n = tile * 16 + col;
    unsigned hs[8], ls[8];
    #pragma unroll
    for (int j = 0; j < 8; ++j) {
        int k = kb * 32 + q * 8 + j;
        float v = (k < Ev) ? W_ih[n * Ev + k] : W_hh[n * Hv + (k - Ev)];
        split_bf16(v, hs[j], ls[j]);
    }
    unsigned* o = wf + (size_t)f * 8;
    #pragma unroll
    for (int d = 0; d < 4; ++d) {
        o[d]     = hs[2 * d] | (hs[2 * d + 1] << 16);
        o[4 + d] = ls[2 * d] | (ls[2 * d + 1] << 16);
    }
}

// ------- kernel B: W1^T for the FC kernel -------
__global__ void build_w1t(const float* __restrict__ W1, float* __restrict__ W1T) {
    int k = blockIdx.x, c = threadIdx.x;
    W1T[k * Hv + c] = W1[c * Hv + k];
}

// ------- kernel C: block-local recurrence -------
// 8 waves x 2 N-tiles. A (emb|h) stored in LDS as per-lane bf16 fragments,
// hi and lo separate, double-buffered. One barrier per step.
__global__ __launch_bounds__(512, 2) void rnn_kernel(
    const int* __restrict__ x_in, const int* __restrict__ x_len,
    const float* __restrict__ emb, const unsigned* __restrict__ wf,
    const float* __restrict__ b_ih, const float* __restrict__ b_hh,
    float* __restrict__ last)
{
    __shared__ unsigned AH[2 * NKB * 256];   // 24 KB: hi fragments, 2 buffers
    __shared__ unsigned AL[2 * NKB * 256];   // 24 KB: lo fragments
    __shared__ int sidx[Mrows * Sv];         // 4 KB token ids

    const int tid = threadIdx.x;
    const int lane = tid & 63, w = tid >> 6;     // wave 0..7
    const int q = lane >> 4, col = lane & 15;
    const int rb = blockIdx.x * Mrows;

    // resident W fragments: tiles 2w, 2w+1  (192 VGPRs)
    bfrag whi[2][NKB], wlo[2][NKB];
    {
        const bfrag* wfv = (const bfrag*)wf;
        #pragma unroll
        for (int i = 0; i < 2; ++i)
            #pragma unroll
            for (int kb = 0; kb < NKB; ++kb) {
                int base = ((kb * 16 + (2 * w + i)) * 64 + lane) * 2;
                whi[i][kb] = wfv[base];
                wlo[i][kb] = wfv[base + 1];
            }
    }

    float bc[2][4];
    #pragma unroll
    for (int i = 0; i < 2; ++i)
        #pragma unroll
        for (int r = 0; r < 4; ++r) {
            int n = (2 * w + i) * 16 + 4 * q + r;
            bc[i][r] = b_ih[n] + b_hh[n];
        }
    const int len_c = x_len[rb + col];

    for (int u = tid; u < Mrows * Sv; u += 512) sidx[u] = x_in[rb * Sv + u];
    // zero h region of buffer 0 (kb 4..11 => words 1024..3071)
    for (int u = tid; u < 2048; u += 512) { AH[1024 + u] = 0u; AL[1024 + u] = 0u; }

    // emb staging geometry: thread stages 4 k-values of one row
    const int em  = tid >> 5;           // row 0..15
    const int ek  = (tid & 31) * 4;     // k offset 0..124
    const int ekb = ek >> 5;            // kb 0..3
    const int edl = ((ek >> 3) & 3) * 16 + em;   // dest lane
    const int ewo = (ek & 4) >> 1;      // word offset 0 or 2

    // stage emb for t=0 into buffer 0
    {
        int idx = x_in[(rb + em) * Sv];
        float4 ev = *(const float4*)&emb[(size_t)idx * Ev + ek];
        unsigned h0, h1, h2, h3, l0, l1, l2, l3;
        split_bf16(ev.x, h0, l0); split_bf16(ev.y, h1, l1);
        split_bf16(ev.z, h2, l2); split_bf16(ev.w, h3, l3);
        int a = ekb * 256 + edl * 4 + ewo;
        *reinterpret_cast<uint2*>(&AH[a]) = make_uint2(h0 | (h1 << 16), h2 | (h3 << 16));
        *reinterpret_cast<uint2*>(&AL[a]) = make_uint2(l0 | (l1 << 16), l2 | (l3 << 16));
    }
    __syncthreads();

    #pragma unroll 1
    for (int t = 0; t < Sv; ++t) {
        const int rbuf = (t & 1) * (NKB * 256);
        const int wbuf = ((t + 1) & 1) * (NKB * 256);

        // prefetch next step's embedding values (global, latency hidden)
        float4 ev;
        const bool pre = (t < Sv - 1);
        if (pre) {
            int idx = sidx[em * Sv + t + 1];
            ev = *(const float4*)&emb[(size_t)idx * Ev + ek];
        }

        // 4 independent accumulator chains
        f4v A0a = {0.f, 0.f, 0.f, 0.f}, A0b = A0a, A1a = A0a, A1b = A0a;

        #pragma unroll
        for (int kb = 0; kb < NKB; ++kb) {
            bfrag ah = *reinterpret_cast<const bfrag*>(&AH[rbuf + kb * 256 + lane * 4]);
            bfrag al = *reinterpret_cast<const bfrag*>(&AL[rbuf + kb * 256 + lane * 4]);
            if (kb & 1) {
                A0b = __builtin_amdgcn_mfma_f32_16x16x32_bf16(whi[0][kb], al, A0b, 0, 0, 0);
                A1b = __builtin_amdgcn_mfma_f32_16x16x32_bf16(whi[1][kb], al, A1b, 0, 0, 0);
                A0a = __builtin_amdgcn_mfma_f32_16x16x32_bf16(whi[0][kb], ah, A0a, 0, 0, 0);
                A1a = __builtin_amdgcn_mfma_f32_16x16x32_bf16(whi[1][kb], ah, A1a, 0, 0, 0);
                A0b = __builtin_amdgcn_mfma_f32_16x16x32_bf16(wlo[0][kb], ah, A0b, 0, 0, 0);
                A1b = __builtin_amdgcn_mfma_f32_16x16x32_bf16(wlo[1][kb], ah, A1b, 0, 0, 0);
            } else {
                A0a = __builtin_amdgcn_mfma_f32_16x16x32_bf16(whi[0][kb], ah, A0a, 0, 0, 0);
                A1a = __builtin_amdgcn_mfma_f32_16x16x32_bf16(whi[1][kb], ah, A1a, 0, 0, 0);
                A0b = __builtin_amdgcn_mfma_f32_16x16x32_bf16(whi[0][kb], al, A0b, 0, 0, 0);
                A1b = __builtin_amdgcn_mfma_f32_16x16x32_bf16(whi[1][kb], al, A1b, 0, 0, 0);
                A0a = __builtin_amdgcn_mfma_f32_16x16x32_bf16(wlo[0][kb], ah, A0a, 0, 0, 0);
                A1a = __builtin_amdgcn_mfma_f32_16x16x32_bf16(wlo[1][kb], ah, A1a, 0, 0, 0);
            }
        }

        // epilogue: D^T lane holds h[m=col][n = ti*16 + 4q + r]
        #pragma unroll
        for (int i = 0; i < 2; ++i) {
            f4v acc = (i == 0) ? (A0a + A0b) : (A1a + A1b);
            const int ti = 2 * w + i;
            const int kb = 4 + (ti >> 1);
            const int dl = ((ti & 1) * 2 + (q >> 1)) * 16 + col;
            const int wo = (q & 1) * 2;
            float hv[4]; unsigned hb[4], lb[4];
            #pragma unroll
            for (int r = 0; r < 4; ++r) {
                hv[r] = fast_tanh(acc[r] + bc[i][r]);
                split_bf16(hv[r], hb[r], lb[r]);
            }
            int a = wbuf + kb * 256 + dl * 4 + wo;
            *reinterpret_cast<uint2*>(&AH[a]) = make_uint2(hb[0] | (hb[1] << 16), hb[2] | (hb[3] << 16));
            *reinterpret_cast<uint2*>(&AL[a]) = make_uint2(lb[0] | (lb[1] << 16), lb[2] | (lb[3] << 16));
            if (t == len_c - 1) {
                float4 v = make_float4(hv[0], hv[1], hv[2], hv[3]);
                *reinterpret_cast<float4*>(&last[(size_t)(rb + col) * Hv + ti * 16 + 4 * q]) = v;
            }
        }
        // stage prefetched emb into write buffer (kb 0..3, disjoint from h)
        if (pre) {
            unsigned h0, h1, h2, h3, l0, l1, l2, l3;
            split_bf16(ev.x, h0, l0); split_bf16(ev.y, h1, l1);
            split_bf16(ev.z, h2, l2); split_bf16(ev.w, h3, l3);
            int a = wbuf + ekb * 256 + edl * 4 + ewo;
            *reinterpret_cast<uint2*>(&AH[a]) = make_uint2(h0 | (h1 << 16), h2 | (h3 << 16));
            *reinterpret_cast<uint2*>(&AL[a]) = make_uint2(l0 | (l1 << 16), l2 | (l3 << 16));
        }
        __syncthreads();
    }
}

// ------- kernel D: fused FC1(relu) + FC2 -------
__global__ __launch_bounds__(256) void fc_kernel(
    const float* __restrict__ last, const float* __restrict__ W1T,
    const float* __restrict__ b1, const float* __restrict__ W2,
    const float* __restrict__ b2, float* __restrict__ out)
{
    __shared__ float At[Hv * AP];
    __shared__ float Wt[KT * Hv];

    const int tid = threadIdx.x;
    const int tr = tid & 3;
    const int tc = tid >> 2;
    const int rb = blockIdx.x * Mrows;

    {
        const int er = tid >> 4;
        const int ek = (tid & 15) * 16;
        #pragma unroll
        for (int qq = 0; qq < 4; ++qq) {
            float4 v = *reinterpret_cast<const float4*>(&last[(rb + er) * Hv + ek + 4 * qq]);
            At[(ek + 4 * qq + 0) * AP + er] = v.x;
            At[(ek + 4 * qq + 1) * AP + er] = v.y;
            At[(ek + 4 * qq + 2) * AP + er] = v.z;
            At[(ek + 4 * qq + 3) * AP + er] = v.w;
        }
    }

    float acc[4][4];
    #pragma unroll
    for (int i = 0; i < 4; ++i)
        #pragma unroll
        for (int j = 0; j < 4; ++j) acc[i][j] = 0.f;

    #pragma unroll 1
    for (int ch = 0; ch < Hv / KT; ++ch) {
        __syncthreads();
        {
            const float4* src = reinterpret_cast<const float4*>(&W1T[ch * KT * Hv]);
            float4* dst = reinterpret_cast<float4*>(Wt);
            #pragma unroll
            for (int qq = 0; qq < 8; ++qq) dst[qq * 256 + tid] = src[qq * 256 + tid];
        }
        __syncthreads();
        #pragma unroll 8
        for (int kk = 0; kk < KT; ++kk) {
            float4 a4 = *reinterpret_cast<const float4*>(&At[(ch * KT + kk) * AP + 4 * tr]);
            float4 w4 = *reinterpret_cast<const float4*>(&Wt[kk * Hv + 4 * tc]);
            float a[4] = {a4.x, a4.y, a4.z, a4.w};
            float wv[4] = {w4.x, w4.y, w4.z, w4.w};
            #pragma unroll
            for (int i = 0; i < 4; ++i)
                #pragma unroll
                for (int j = 0; j < 4; ++j)
                    acc[i][j] = fmaf(a[i], wv[j], acc[i][j]);
        }
    }
    __syncthreads();

    {
        float bj[4];
        #pragma unroll
        for (int j = 0; j < 4; ++j) bj[j] = b1[4 * tc + j];
        #pragma unroll
        for (int i = 0; i < 4; ++i) {
            float4 v;
            v.x = fmaxf(acc[i][0] + bj[0], 0.f);
            v.y = fmaxf(acc[i][1] + bj[1], 0.f);
            v.z = fmaxf(acc[i][2] + bj[2], 0.f);
            v.w = fmaxf(acc[i][3] + bj[3], 0.f);
            *reinterpret_cast<float4*>(&Wt[(4 * tr + i) * 260 + 4 * tc]) = v;
        }
    }
    __syncthreads();

    for (int p = tid; p < Mrows * Cv; p += 256) {
        int r = p & 15, cc = p >> 4;
        float s = b2[cc];
        for (int k4 = 0; k4 < Hv / 4; ++k4) {
            float4 yv = *reinterpret_cast<const float4*>(&Wt[r * 260 + 4 * k4]);
            float4 wv = *reinterpret_cast<const float4*>(&W2[cc * Hv + 4 * k4]);
            s = fmaf(yv.x, wv.x, s);
            s = fmaf(yv.y, wv.y, s);
            s = fmaf(yv.z, wv.z, s);
            s = fmaf(yv.w, wv.w, s);
        }
        out[(rb + r) * Cv + cc] = s;
    }
}

extern "C" void kernel_launch(void* const* d_in, const int* in_sizes, int n_in,
                              void* d_out, int out_size, void* d_ws, size_t ws_size,
                              hipStream_t stream) {
    const int*   x_in  = (const int*)  d_in[0];
    const int*   x_len = (const int*)  d_in[1];
    const float* emb   = (const float*)d_in[2];
    const float* W_ih  = (const float*)d_in[3];
    const float* W_hh  = (const float*)d_in[4];
    const float* b_ih  = (const float*)d_in[5];
    const float* b_hh  = (const float*)d_in[6];
    const float* W1    = (const float*)d_in[7];
    const float* b1    = (const float*)d_in[8];
    const float* W2    = (const float*)d_in[9];
    const float* b2    = (const float*)d_in[10];
    float* out = (float*)d_out;

    float*    last = (float*)d_ws;                     // 4 MB
    float*    W1T  = last + (size_t)Bv * Hv;           // 256 KB
    unsigned* wf   = (unsigned*)(W1T + Hv * Hv);       // 384 KB

    build_wfrag<<<48, 256, 0, stream>>>(W_ih, W_hh, wf);
    build_w1t<<<Hv, Hv, 0, stream>>>(W1, W1T);
    rnn_kernel<<<Bv / Mrows, 512, 0, stream>>>(x_in, x_len, emb, wf, b_ih, b_hh, last);
    fc_kernel<<<Bv / Mrows, 256, 0, stream>>>(last, W1T, b1, W2, b2, out);
}